// Round 10
// baseline (348.540 us; speedup 1.0000x reference)
//
#include <hip/hip_runtime.h>
#include <hip/hip_bf16.h>

#define DEV __device__ __forceinline__

typedef __bf16 bf16x8 __attribute__((ext_vector_type(8)));
typedef float f32x4 __attribute__((ext_vector_type(4)));

DEV float ldflex(const void* p, long i, int bf) {
    return bf ? __bfloat162float(((const __hip_bfloat16*)p)[i]) : ((const float*)p)[i];
}
DEV bf16x8 ldfrag(const __hip_bfloat16* p) { return *(const bf16x8*)(const void*)p; }

// XCD-aware block swizzle (T1); requires nwg % 8 == 0 (512/256/128 at call sites).
DEV int xcd_swz(int bid, int nwg) {
    return (bid & 7) * (nwg >> 3) + (bid >> 3);
}

// ---------------- generic pool cell (for fused tails) ----------------
DEV void pool_cell(const float* __restrict__ in, float* __restrict__ out,
                   int Di, int Hi, int Wi, int Do, int Ho, int Wo, int stride, int idx) {
    int w = idx % Wo; int r = idx / Wo;
    int h = r % Ho;   int d = r / Ho;
    float m = 0.f;
    for (int kd = 0; kd < 3; ++kd) {
        int id = d * stride + kd - 1;
        if (id < 0 || id >= Di) continue;
        for (int kh = 0; kh < 3; ++kh) {
            int ih = h * stride + kh - 1;
            if (ih < 0 || ih >= Hi) continue;
            for (int kw = 0; kw < 3; ++kw) {
                int iw = w * stride + kw - 1;
                if (iw < 0 || iw >= Wi) continue;
                m = fmaxf(m, in[((size_t)id * Hi + ih) * Wi + iw]);
            }
        }
    }
    out[idx] = m;
}

// ---------------- K1: workspace init (idxmap/cnt/occ1 fills + slab BORDER rings) -----
struct InitArgs {
    char* b0; char* b1; char* b2; char* b3;   // idxmap / cnt / slab base (xP0A) / occ1
    int u0, u1, u3;                           // uint4 counts for b0/b1/b3
    const void* probe; int* flag;
};

__global__ void init_all(InitArgs a) {
    if (blockIdx.x == 0 && threadIdx.x == 0) {
        const unsigned short* u = (const unsigned short*)a.probe;
        int sane = 0;
        for (int i = 0; i < 256; ++i) {
            unsigned short v = u[i];
            int e = (v >> 7) & 0xFF;
            if (v == 0 || (e >= 107 && e <= 147)) sane++;
        }
        *a.flag = (sane >= 192) ? 1 : 0;   // 1 = bf16 storage
    }
    const int P0 = 169000;   // 10*130*130 px (xP0A/xP0B, 64 B/px)
    const int P1 = 26136;    // 6*66*66    px (xP1A/xP1B, 128 B/px)
    const int P2 = 4624;     // 4*34*34    px (xP2A/xP2B, 128 B/px)
    int totalA = a.u0 + a.u1 + a.u3;
    int total = totalA + 2 * P0 + 2 * P1 + 2 * P2;
    int stride = gridDim.x * 256;
    for (int u = blockIdx.x * 256 + threadIdx.x; u < total; u += stride) {
        if (u < a.u0) {
            uint4 v = {0xFFFFFFFFu, 0xFFFFFFFFu, 0xFFFFFFFFu, 0xFFFFFFFFu};
            ((uint4*)a.b0)[u] = v;
        } else if (u < a.u0 + a.u1) {
            uint4 v = {0u, 0u, 0u, 0u};
            ((uint4*)a.b1)[u - a.u0] = v;
        } else if (u < totalA) {
            uint4 v = {0u, 0u, 0u, 0u};
            ((uint4*)a.b3)[u - a.u0 - a.u1] = v;     // occ1 = 0 (voxel kernel scatters 1s)
        } else {
            int p = u - totalA;
            uint4 z = {0u, 0u, 0u, 0u};
            if (p < 2 * P0) {
                char* base = a.b2 + (p < P0 ? 0 : 10816000);
                p = (p < P0) ? p : p - P0;
                int w = p % 130; int r = p / 130; int h = r % 130; int d = r / 130;
                if (d == 0 || d == 9 || h == 0 || h == 129 || w == 0 || w == 129) {
                    uint4* q = (uint4*)(base + (size_t)p * 64);
                    q[0] = z; q[1] = z; q[2] = z; q[3] = z;
                }
            } else if ((p -= 2 * P0) < 2 * P1) {
                char* base = a.b2 + 21632000 + (p < P1 ? 0 : 3345408);
                p = (p < P1) ? p : p - P1;
                int w = p % 66; int r = p / 66; int h = r % 66; int d = r / 66;
                if (d == 0 || d == 5 || h == 0 || h == 65 || w == 0 || w == 65) {
                    uint4* q = (uint4*)(base + (size_t)p * 128);
#pragma unroll
                    for (int k = 0; k < 8; ++k) q[k] = z;
                }
            } else {
                p -= 2 * P1;
                char* base = a.b2 + 28322816 + (p < P2 ? 0 : 591872);
                p = (p < P2) ? p : p - P2;
                int w = p % 34; int r = p / 34; int h = r % 34; int d = r / 34;
                if (d == 0 || d == 3 || h == 0 || h == 33 || w == 0 || w == 33) {
                    uint4* q = (uint4*)(base + (size_t)p * 128);
#pragma unroll
                    for (int k = 0; k < 8; ++k) q[k] = z;
                }
            }
        }
    }
}

// ---------------- K2: flat weight conversion + point lists ----------------
// R8 used dim3(864,31) = 26784 workgroups; ~84% exited immediately (each segment got
// 864 blocks regardless of its n). CP dispatches WGs at ~1-2/cycle -> ~10-18us wasted.
// Flat 1-D grid of exactly sum(ceil(n/256)) = 4366 blocks; block-aligned segment table
// resolved by a wave-uniform SALU compare chain (constant indices only, no divergence).
struct CvtDesc { const void* src; int n; int off; int cin; int cout; };
struct CvtArgs { CvtDesc d[31]; int bstart[32]; };   // d[30] = list-build pseudo-segment

__global__ void cvt_build(CvtArgs a, __hip_bfloat16* __restrict__ wf,
                          float* __restrict__ bn, const int* __restrict__ flagp,
                          const int* __restrict__ p2v, int* __restrict__ cnt,
                          int* __restrict__ list) {
    int b = blockIdx.x;
    int seg = 0;
#pragma unroll
    for (int k = 1; k < 31; ++k) if (b >= a.bstart[k]) seg = k;   // uniform, SALU
    int segbase = 0;
#pragma unroll
    for (int k = 1; k < 31; ++k) if (seg == k) segbase = a.bstart[k];
    int i = (b - segbase) * 256 + threadIdx.x;

    if (seg == 30) {                       // build_lists segment (200000 points)
        if (i >= 200000) return;
        int v = p2v[i];
        int slot = atomicAdd(&cnt[v], 1);
        if (slot < 20) list[v * 20 + slot] = i;
        return;
    }
    // select descriptor fields with constant-index chain (uniform -> s_cselect)
    const void* src = a.d[0].src; int n = a.d[0].n, off = a.d[0].off;
    int cin = a.d[0].cin, cout = a.d[0].cout;
#pragma unroll
    for (int k = 1; k < 30; ++k)
        if (seg == k) { src = a.d[k].src; n = a.d[k].n; off = a.d[k].off;
                        cin = a.d[k].cin; cout = a.d[k].cout; }
    if (i >= n) return;
    float v = ldflex(src, i, *flagp);
    if (cin == 0) { bn[off + i] = v; return; }
    int KB = cin >> 5, NH = cout >> 4;
    int co = i / (cin * 27);
    int rem = i % (cin * 27);
    int ci = rem / 27, tap = rem % 27;
    int kb = ci >> 5, q = (ci >> 3) & 3, j = ci & 7;
    int half = co >> 4, n2 = co & 15, lane = q * 16 + n2;
    (void)KB;
    wf[off + ((((tap * KB + kb) * NH + half) << 9) + lane * 8 + j)] = __float2bfloat16(v);
}

// ---------------- K3: voxel-major fused VFE ----------------
// (scatter + sort + vfe + occ1 inverse-pool; numerics bit-identical to 3-kernel path)
__global__ __launch_bounds__(256) void voxel_vfe(
    const void* __restrict__ points, const void* __restrict__ voxels,
    const void* __restrict__ w_in, const void* __restrict__ s_in, const void* __restrict__ t_in,
    const int* __restrict__ coors, const int* __restrict__ cnt,
    const int* __restrict__ list, int* __restrict__ idxmap,
    float* __restrict__ occ1, __hip_bfloat16* __restrict__ hbuf,
    const int* __restrict__ flagp) {
    const int N = 200000;
    __shared__ float lw[256], lsc[32], lbi[32];
    int bf = *flagp;
    if (threadIdx.x < 256) lw[threadIdx.x] = ldflex(w_in, threadIdx.x, bf);
    if (threadIdx.x < 32) {
        lsc[threadIdx.x] = ldflex(s_in, threadIdx.x, bf);
        lbi[threadIdx.x] = ldflex(t_in, threadIdx.x, bf);
    }
    __syncthreads();
    int v = blockIdx.x * 256 + threadIdx.x;
    if (v >= 40000) return;
    if (v < 16) ((unsigned int*)(hbuf + 40000 * 32))[v] = 0u;   // zero row for holes

    int x = coors[v * 4 + 1], y = coors[v * 4 + 2], z = coors[v * 4 + 3];
    idxmap[((size_t)z * 256 + y) * 256 + x] = v;
    // occ1 inverse-pool scatter: valid d satisfy |z-2d|<=1 -> d in [z>>1, (z+1)>>1]
    for (int dd = z >> 1; dd <= ((z + 1) >> 1) && dd < 8; ++dd)
        for (int hh = y >> 1; hh <= ((y + 1) >> 1) && hh < 128; ++hh)
            for (int ww = x >> 1; ww <= ((x + 1) >> 1) && ww < 128; ++ww)
                occ1[((size_t)dd * 128 + hh) * 128 + ww] = 1.f;

    int c_ = min(cnt[v], 20);
    int idxs[20];
    for (int k = 0; k < c_; ++k) idxs[k] = list[v * 20 + k];
    for (int i = 1; i < c_; ++i) {
        int key = idxs[i]; int j = i - 1;
        while (j >= 0 && idxs[j] > key) { idxs[j + 1] = idxs[j]; --j; }
        idxs[j + 1] = key;
    }
    float vx0 = ldflex(voxels, v * 4 + 0, bf);
    float vx1 = ldflex(voxels, v * 4 + 1, bf);
    float vx2 = ldflex(voxels, v * 4 + 2, bf);
    float vx3 = ldflex(voxels, v * 4 + 3, bf);
    float acc[32];
#pragma unroll
    for (int j = 0; j < 32; ++j) acc[j] = 0.f;
    int msum = min(c_, 5);
    for (int s = 0; s < msum; ++s) {        // ascending point index = old slot order
        int i = idxs[s];
        float p0 = ldflex(points, i, bf);
        float p1 = ldflex(points, N + i, bf);
        float p2 = ldflex(points, 2 * N + i, bf);
        float p3 = ldflex(points, 3 * N + i, bf);
        float f0 = vx0 - p0, f1 = vx1 - p1, f2 = vx2 - p2, f3 = vx3 - p3;
        float mult = (s == 0) ? (float)(20 - c_ + 1) : 1.f;
#pragma unroll
        for (int oo = 0; oo < 32; ++oo) {
            float d = f0 * lw[oo * 8 + 0] + f1 * lw[oo * 8 + 1] + f2 * lw[oo * 8 + 2] +
                      f3 * lw[oo * 8 + 3] + p0 * lw[oo * 8 + 4] + p1 * lw[oo * 8 + 5] +
                      p2 * lw[oo * 8 + 6] + p3 * lw[oo * 8 + 7];
            float r = fmaxf(d * lsc[oo] + lbi[oo], 0.f) * mult;
            acc[oo] += __bfloat162float((__bf16)r);   // replicate old per-slot bf16 round
        }
    }
    __hip_bfloat16* o = hbuf + (size_t)v * 32;
#pragma unroll
    for (int g = 0; g < 4; ++g) {
        bf16x8 pack;
#pragma unroll
        for (int j = 0; j < 8; ++j) pack[j] = (__bf16)(acc[g * 8 + j] * 0.05f);
        *(bf16x8*)(void*)(o + g * 8) = pack;
    }
}

// ---------------- conv0: sparse gather implicit-GEMM MFMA, 4 tiles/wave (+pool tail) ----
__global__ __launch_bounds__(256) void conv0_mfma(
    const __hip_bfloat16* __restrict__ hb, const int* __restrict__ idxmap,
    __hip_bfloat16* __restrict__ out,                 // padded (10,130,130,32)
    const __hip_bfloat16* __restrict__ wf, const float* __restrict__ bns,
    const float* __restrict__ occ, float* __restrict__ pdst) {
    if (blockIdx.x >= 512) {               // tail: occ1 -> occ2 (16384 cells, 64 blocks)
        int t = (blockIdx.x - 512) * 256 + threadIdx.x;
        if (t < 16384) pool_cell(occ, pdst, 8, 128, 128, 4, 64, 64, 2, t);
        return;
    }
    int bid = xcd_swz(blockIdx.x, 512);
    int wave = (bid * 256 + threadIdx.x) >> 6;        // 2048 waves (4-tile groups)
    int lane = threadIdx.x & 63;
    int twg = wave & 1; int r = wave >> 1;
    int h = r & 127;    int d = r >> 7;
    int w0 = twg * 64;
    int q = lane >> 4, n = lane & 15;

    f32x4 acc[4][2];
#pragma unroll
    for (int t = 0; t < 4; ++t)
#pragma unroll
        for (int i = 0; i < 2; ++i) acc[t][i] = (f32x4){0.f, 0.f, 0.f, 0.f};

    const float* op = occ + ((size_t)(d * 128 + h)) * 128 + w0;
    bool any = false;
#pragma unroll
    for (int t = 0; t < 4; ++t) any = any || (op[t * 16 + n] != 0.f);
    if (__ballot(any)) {
#pragma unroll
        for (int kd = 0; kd < 3; ++kd) {
            int id = d * 2 + kd - 1;
            if (id < 0) continue;
#pragma unroll
            for (int kh = 0; kh < 3; ++kh) {
                int ih = h * 2 + kh - 1;
                if (ih < 0) continue;
                const int* ip = idxmap + ((size_t)id * 256 + ih) * 256;
#pragma unroll
                for (int kw = 0; kw < 3; ++kw) {
                    int tap = (kd * 3 + kh) * 3 + kw;
                    bf16x8 A[4];
#pragma unroll
                    for (int t = 0; t < 4; ++t) {
                        int iw = (w0 + t * 16 + n) * 2 + kw - 1;
                        int v = (iw >= 0) ? ip[iw] : -1;
                        int vv = (v >= 0) ? v : 40000;          // row 40000 = zeros
                        A[t] = ldfrag(hb + (size_t)vv * 32 + q * 8);
                    }
#pragma unroll
                    for (int i = 0; i < 2; ++i) {
                        bf16x8 B = ldfrag(wf + ((tap * 2 + i) << 9) + lane * 8);
#pragma unroll
                        for (int t = 0; t < 4; ++t)
                            acc[t][i] = __builtin_amdgcn_mfma_f32_16x16x32_bf16(
                                A[t], B, acc[t][i], 0, 0, 0);
                    }
                }
            }
        }
    }
#pragma unroll
    for (int t = 0; t < 4; ++t)
#pragma unroll
        for (int half = 0; half < 2; ++half) {
            int co = half * 16 + n;
            float s = bns[co], b = bns[32 + co];
#pragma unroll
            for (int r2 = 0; r2 < 4; ++r2) {
                int mm = t * 16 + q * 4 + r2;
                float oc = op[mm];
                float vv = fmaxf(acc[t][half][r2] * s + b, 0.f) * oc;
                out[((size_t)((d + 1) * 130 + (h + 1)) * 130 + (w0 + mm + 1)) * 32 + co] =
                    __float2bfloat16(vv);
            }
        }
}

// ---------------- dense implicit-GEMM MFMA conv: TILES tiles, NHP halves (+pool tail) ----
template <int CIN, int COUT, int STRIDE, int NHP, int TILES>
__global__ __launch_bounds__(256) void conv_mfma(
    const __hip_bfloat16* __restrict__ in, __hip_bfloat16* __restrict__ out,
    const __hip_bfloat16* __restrict__ wf, const float* __restrict__ bns,
    const float* __restrict__ occ,
    int Hp, int Wp, int Do, int Ho, int Wo, int OHp, int OWp,
    int mainBlocks, const float* psrc, float* pdst,
    int pDi, int pHi, int pWi, int pDo, int pHo, int pWo, int pStride, int pcount) {
    constexpr int KB = CIN / 32, NH = COUT / 16, NG = NH / NHP;
    if ((int)blockIdx.x >= mainBlocks) {
        int t = (blockIdx.x - mainBlocks) * 256 + threadIdx.x;
        if (t < pcount) pool_cell(psrc, pdst, pDi, pHi, pWi, pDo, pHo, pWo, pStride, t);
        return;
    }
    int bid = xcd_swz(blockIdx.x, mainBlocks);
    int gw = (bid * 256 + threadIdx.x) >> 6;
    int lane = threadIdx.x & 63;
    int hg = gw % NG;
    int wave = gw / NG;
    int ngw = (Wo >> 4) / TILES;
    int twg = wave % ngw; int r = wave / ngw;
    int h = r % Ho; int d = r / Ho;
    int w0 = twg * TILES * 16;
    int q = lane >> 4, n = lane & 15;

    f32x4 acc[TILES][NHP];
#pragma unroll
    for (int t = 0; t < TILES; ++t)
#pragma unroll
        for (int i = 0; i < NHP; ++i) acc[t][i] = (f32x4){0.f, 0.f, 0.f, 0.f};

    const float* op = occ + ((size_t)(d * Ho + h)) * Wo + w0;
    bool any = false;
#pragma unroll
    for (int t = 0; t < TILES; ++t) any = any || (op[t * 16 + n] != 0.f);
    if (__ballot(any)) {
#pragma unroll
        for (int kd = 0; kd < 3; ++kd) {
#pragma unroll
            for (int kh = 0; kh < 3; ++kh) {
#pragma unroll
                for (int kw = 0; kw < 3; ++kw) {
                    int tap = (kd * 3 + kh) * 3 + kw;
                    const __hip_bfloat16* ip = in +
                        ((size_t)((d * STRIDE + kd) * Hp + (h * STRIDE + kh)) * Wp +
                         (w0 * STRIDE + kw)) * CIN;
#pragma unroll
                    for (int kb = 0; kb < KB; ++kb) {
                        bf16x8 A[TILES];
#pragma unroll
                        for (int t = 0; t < TILES; ++t)
                            A[t] = ldfrag(ip + ((t * 16 + n) * STRIDE) * CIN + kb * 32 + q * 8);
#pragma unroll
                        for (int i = 0; i < NHP; ++i) {
                            int half = hg * NHP + i;
                            bf16x8 B = ldfrag(
                                wf + (((tap * KB + kb) * NH + half) << 9) + lane * 8);
#pragma unroll
                            for (int t = 0; t < TILES; ++t)
                                acc[t][i] = __builtin_amdgcn_mfma_f32_16x16x32_bf16(
                                    A[t], B, acc[t][i], 0, 0, 0);
                        }
                    }
                }
            }
        }
    }
#pragma unroll
    for (int t = 0; t < TILES; ++t)
#pragma unroll
        for (int i = 0; i < NHP; ++i) {
            int co = (hg * NHP + i) * 16 + n;
            float s = bns[co], b = bns[COUT + co];
#pragma unroll
            for (int r2 = 0; r2 < 4; ++r2) {
                int mm = t * 16 + q * 4 + r2;
                float oc = op[mm];
                float vv = fmaxf(acc[t][i][r2] * s + b, 0.f) * oc;
                out[((size_t)((d + 1) * OHp + (h + 1)) * OWp + (w0 + mm + 1)) * COUT + co] =
                    __float2bfloat16(vv);
            }
        }
}

// ---------------- final conv 64->128, NCDHW typed output ----------------
__global__ __launch_bounds__(256) void conv_out_mfma(
    const __hip_bfloat16* __restrict__ in,            // padded (4,34,34,64)
    void* __restrict__ outv,
    const __hip_bfloat16* __restrict__ wf, const float* __restrict__ bns,
    const float* __restrict__ occ, const int* __restrict__ flagp) {
    constexpr int KB = 2, NH = 8;
    int bid = xcd_swz(blockIdx.x, 256);
    int gw = (bid * 256 + threadIdx.x) >> 6;          // 1024 waves
    int lane = threadIdx.x & 63;
    int hg = gw & 7;
    int wave = gw >> 3;
    int tw = wave & 1; int r = wave >> 1;
    int h = r & 31;    int d = r >> 5;
    int w0 = tw * 16;
    int q = lane >> 4, n = lane & 15;

    f32x4 acc = {0.f, 0.f, 0.f, 0.f};
    const float* op = occ + ((size_t)(d * 32 + h)) * 32 + w0;
    float ocn = op[n];
    if (__ballot(ocn != 0.f)) {
#pragma unroll
        for (int kd = 0; kd < 3; ++kd) {
#pragma unroll
            for (int kh = 0; kh < 3; ++kh) {
#pragma unroll
                for (int kw = 0; kw < 3; ++kw) {
                    int tap = (kd * 3 + kh) * 3 + kw;
                    const __hip_bfloat16* ip = in +
                        ((size_t)((d + kd) * 34 + (h + kh)) * 34 + (w0 + kw)) * 64;
#pragma unroll
                    for (int kb = 0; kb < KB; ++kb) {
                        bf16x8 A = ldfrag(ip + n * 64 + kb * 32 + q * 8);
                        acc = __builtin_amdgcn_mfma_f32_16x16x32_bf16(
                            A, ldfrag(wf + (((tap * KB + kb) * NH + hg) << 9) + lane * 8),
                            acc, 0, 0, 0);
                    }
                }
            }
        }
    }
    int bf = *flagp;
    int co = hg * 16 + n;
    float s = bns[co], b = bns[128 + co];
#pragma unroll
    for (int r2 = 0; r2 < 4; ++r2) {
        int mm = q * 4 + r2;
        float oc = op[mm];
        float vv = fmaxf(acc[r2] * s + b, 0.f) * oc;
        size_t off = (size_t)co * 2048 + ((size_t)(d * 32 + h)) * 32 + (w0 + mm);
        if (bf) ((__hip_bfloat16*)outv)[off] = __float2bfloat16(vv);
        else    ((float*)outv)[off] = vv;
    }
}

// ---------------- launch (13 dispatches) ----------------
extern "C" void kernel_launch(void* const* d_in, const int* in_sizes, int n_in,
                              void* d_out, int out_size, void* d_ws, size_t ws_size,
                              hipStream_t stream) {
    const void* points = d_in[0];
    const void* voxels = d_in[1];
    const void* w_in   = d_in[2];
    const void* s_in   = d_in[3];
    const void* t_in   = d_in[4];
    const int* coors = (const int*)d_in[35];
    const int* p2v   = (const int*)d_in[36];

    char* ws = (char*)d_ws;
    __hip_bfloat16* wf   = (__hip_bfloat16*)(ws + 0);
    float*          bn   = (float*)(ws + 1835008);
    __hip_bfloat16* hbuf = (__hip_bfloat16*)(ws + 4194304);    // 40001*32 bf16
    int*   idxmap = (int*)(ws + 8388608);                      // 4 MiB
    __hip_bfloat16* xP0A = (__hip_bfloat16*)(ws + 12582912);
    __hip_bfloat16* xP0B = (__hip_bfloat16*)(ws + 23398912);
    __hip_bfloat16* xP1A = (__hip_bfloat16*)(ws + 34214912);
    __hip_bfloat16* xP1B = (__hip_bfloat16*)(ws + 37560320);
    __hip_bfloat16* xP2A = (__hip_bfloat16*)(ws + 40905728);
    __hip_bfloat16* xP2B = (__hip_bfloat16*)(ws + 41497600);
    float* occ1 = (float*)(ws + 42089472);                     // 512 KB
    float* occ2 = (float*)(ws + 42613760);
    float* occ3 = (float*)(ws + 42679296);
    float* occ4 = (float*)(ws + 42687488);
    int*   cnt  = (int*)(ws + 42695680);
    int*   list = (int*)(ws + 43015680);                       // 3.2 MB
    int*   flag = (int*)(ws + 47015680);

    // K1: idxmap=-1, cnt=0, occ1=0, slab border rings=0, + dtype probe
    InitArgs ia;
    ia.b0 = (char*)idxmap; ia.u0 = 4194304 / 16;
    ia.b1 = (char*)cnt;    ia.u1 = 160000 / 16;
    ia.b3 = (char*)occ1;   ia.u3 = 524288 / 16;
    ia.b2 = (char*)xP0A;
    ia.probe = points; ia.flag = flag;
    init_all<<<2048, 256, 0, stream>>>(ia);

    static const int widx[30] = {5,6,7, 8,9,10, 11,12,13, 14,15,16, 17,18,19,
                                 20,21,22, 23,24,25, 26,27,28, 29,30,31, 32,33,34};
    static const int wnn[30]  = {27648,32,32, 27648,32,32, 27648,32,32,
                                 55296,64,64, 110592,64,64, 110592,64,64,
                                 110592,64,64, 110592,64,64, 110592,64,64,
                                 221184,128,128};
    static const int woff[30] = {0,0,32, 27648,64,96, 55296,128,160,
                                 82944,192,256, 138240,320,384, 248832,448,512,
                                 359424,576,640, 470016,704,768, 580608,832,896,
                                 691200,960,1088};
    static const int wcin[30]  = {32,0,0, 32,0,0, 32,0,0, 32,0,0, 64,0,0,
                                  64,0,0, 64,0,0, 64,0,0, 64,0,0, 64,0,0};
    static const int wcout[30] = {32,0,0, 32,0,0, 32,0,0, 64,0,0, 64,0,0,
                                  64,0,0, 64,0,0, 64,0,0, 64,0,0, 128,0,0};
    CvtArgs ca;
    int nb = 0;
    for (int i = 0; i < 30; ++i) {
        ca.d[i] = CvtDesc{ d_in[widx[i]], wnn[i], woff[i], wcin[i], wcout[i] };
        ca.bstart[i] = nb;
        nb += (wnn[i] + 255) / 256;
    }
    ca.d[30] = CvtDesc{ nullptr, 200000, 0, 0, 0 };
    ca.bstart[30] = nb;
    nb += (200000 + 255) / 256;            // total = 4366 blocks
    ca.bstart[31] = nb;
    // K2: flat cvt_weights + build_lists (exactly nb blocks, no wasted dispatch)
    cvt_build<<<nb, 256, 0, stream>>>(ca, wf, bn, flag, p2v, cnt, list);

    // K3: fused voxel-major VFE (scatter + sort + vfe + occ1)
    voxel_vfe<<<157, 256, 0, stream>>>(points, voxels, w_in, s_in, t_in,
                                       coors, cnt, list, idxmap, occ1, hbuf, flag);

    // stage 0: -> (8,128,128) x32   (512 main blocks; conv0 tail computes occ2)
    conv0_mfma<<<576, 256, 0, stream>>>(hbuf, idxmap, xP0A, wf + 0, bn + 0, occ1, occ2);
    conv_mfma<32, 32, 1, 2, 4><<<520, 256, 0, stream>>>(
        xP0A, xP0B, wf + 27648, bn + 64, occ1, 130, 130, 8, 128, 128, 130, 130,
        512, occ2, occ3, 4, 64, 64, 2, 32, 32, 2, 2048);
    conv_mfma<32, 32, 1, 2, 4><<<520, 256, 0, stream>>>(
        xP0B, xP0A, wf + 55296, bn + 128, occ1, 130, 130, 8, 128, 128, 130, 130,
        512, occ3, occ4, 2, 32, 32, 2, 32, 32, 1, 2048);

    // stage 1: -> (4,64,64) x64
    conv_mfma<32, 64, 2, 2, 2><<<256, 256, 0, stream>>>(
        xP0A, xP1A, wf + 82944, bn + 192, occ2, 130, 130, 4, 64, 64, 66, 66,
        256, nullptr, nullptr, 0, 0, 0, 0, 0, 0, 1, 0);
    conv_mfma<64, 64, 1, 2, 2><<<256, 256, 0, stream>>>(
        xP1A, xP1B, wf + 138240, bn + 320, occ2, 66, 66, 4, 64, 64, 66, 66,
        256, nullptr, nullptr, 0, 0, 0, 0, 0, 0, 1, 0);
    conv_mfma<64, 64, 1, 2, 2><<<256, 256, 0, stream>>>(
        xP1B, xP1A, wf + 248832, bn + 448, occ2, 66, 66, 4, 64, 64, 66, 66,
        256, nullptr, nullptr, 0, 0, 0, 0, 0, 0, 1, 0);

    // stage 2: -> (2,32,32) x64
    conv_mfma<64, 64, 2, 1, 1><<<128, 256, 0, stream>>>(
        xP1A, xP2A, wf + 359424, bn + 576, occ3, 66, 66, 2, 32, 32, 34, 34,
        128, nullptr, nullptr, 0, 0, 0, 0, 0, 0, 1, 0);
    conv_mfma<64, 64, 1, 1, 1><<<128, 256, 0, stream>>>(
        xP2A, xP2B, wf + 470016, bn + 704, occ3, 34, 34, 2, 32, 32, 34, 34,
        128, nullptr, nullptr, 0, 0, 0, 0, 0, 0, 1, 0);
    conv_mfma<64, 64, 1, 1, 1><<<128, 256, 0, stream>>>(
        xP2B, xP2A, wf + 580608, bn + 832, occ3, 34, 34, 2, 32, 32, 34, 34,
        128, nullptr, nullptr, 0, 0, 0, 0, 0, 0, 1, 0);

    // final: -> (128,2,32,32)
    conv_out_mfma<<<256, 256, 0, stream>>>(xP2A, d_out, wf + 691200, bn + 960, occ4, flag);
}

// Round 11
// 337.941 us; speedup vs baseline: 1.0314x; 1.0314x over previous
//
#include <hip/hip_runtime.h>
#include <hip/hip_bf16.h>

#define DEV __device__ __forceinline__

typedef __bf16 bf16x8 __attribute__((ext_vector_type(8)));
typedef float f32x4 __attribute__((ext_vector_type(4)));

DEV float ldflex(const void* p, long i, int bf) {
    return bf ? __bfloat162float(((const __hip_bfloat16*)p)[i]) : ((const float*)p)[i];
}
DEV bf16x8 ldfrag(const __hip_bfloat16* p) { return *(const bf16x8*)(const void*)p; }

// XCD-aware block swizzle (T1); requires nwg % 8 == 0 (512/256/128 at call sites).
DEV int xcd_swz(int bid, int nwg) {
    return (bid & 7) * (nwg >> 3) + (bid >> 3);
}

// ---------------- generic pool cell (for fused tails) ----------------
DEV void pool_cell(const float* __restrict__ in, float* __restrict__ out,
                   int Di, int Hi, int Wi, int Do, int Ho, int Wo, int stride, int idx) {
    int w = idx % Wo; int r = idx / Wo;
    int h = r % Ho;   int d = r / Ho;
    float m = 0.f;
    for (int kd = 0; kd < 3; ++kd) {
        int id = d * stride + kd - 1;
        if (id < 0 || id >= Di) continue;
        for (int kh = 0; kh < 3; ++kh) {
            int ih = h * stride + kh - 1;
            if (ih < 0 || ih >= Hi) continue;
            for (int kw = 0; kw < 3; ++kw) {
                int iw = w * stride + kw - 1;
                if (iw < 0 || iw >= Wi) continue;
                m = fmaxf(m, in[((size_t)id * Hi + ih) * Wi + iw]);
            }
        }
    }
    out[idx] = m;
}

// ---------------- K1: tiny — cnt zero (must precede list atomics) + dtype probe ------
__global__ void init_cnt(int* __restrict__ cnt, const void* __restrict__ probe,
                         int* __restrict__ flag) {
    if (blockIdx.x == 0) {                 // wave-parallel probe (== old serial loop)
        __shared__ int ss[4];
        const unsigned short* u = (const unsigned short*)probe;
        unsigned short v = u[threadIdx.x];
        int e = (v >> 7) & 0xFF;
        int ok = (v == 0 || (e >= 107 && e <= 147)) ? 1 : 0;
        unsigned long long m = __ballot(ok);
        if ((threadIdx.x & 63) == 0) ss[threadIdx.x >> 6] = __popcll(m);
        __syncthreads();
        if (threadIdx.x == 0)
            *flag = (ss[0] + ss[1] + ss[2] + ss[3] >= 192) ? 1 : 0;
    }
    int t = blockIdx.x * 256 + threadIdx.x;
    if (t < 10000) {
        uint4 z = {0u, 0u, 0u, 0u};
        ((uint4*)cnt)[t] = z;
    }
}

// ---------------- K2: y-grid weight conversion + point lists + init fills ------------
// R8-proven y-grid form (R10's flat form regressed). y<30 = weight/bn segments,
// y==30 = list build, y==31 = init fills (idxmap=-1, occ1=0, slab border rings) —
// write-disjoint from all other segments, so fill BW overlaps cvt work.
struct CvtDesc { const void* src; int n; int off; int cin; int cout; };
struct CvtArgs { CvtDesc d[30]; };

__global__ void cvt_build(CvtArgs a, __hip_bfloat16* __restrict__ wf,
                          float* __restrict__ bn, const int* __restrict__ flagp,
                          const int* __restrict__ p2v, int* __restrict__ cnt,
                          int* __restrict__ list, int* __restrict__ idxmap,
                          float* __restrict__ occ1, char* __restrict__ slab) {
    if (blockIdx.y == 31) {                // init fills (grid-stride over 864 blocks)
        const int U0 = 262144, U3 = 32768; // idxmap / occ1 uint4 counts
        const int P0 = 169000, P1 = 26136, P2 = 4624;
        int totalA = U0 + U3;
        int total = totalA + 2 * P0 + 2 * P1 + 2 * P2;
        for (int u = blockIdx.x * 256 + threadIdx.x; u < total; u += 864 * 256) {
            if (u < U0) {
                uint4 v = {0xFFFFFFFFu, 0xFFFFFFFFu, 0xFFFFFFFFu, 0xFFFFFFFFu};
                ((uint4*)idxmap)[u] = v;
            } else if (u < totalA) {
                uint4 v = {0u, 0u, 0u, 0u};
                ((uint4*)occ1)[u - U0] = v;
            } else {
                int p = u - totalA;
                uint4 z = {0u, 0u, 0u, 0u};
                if (p < 2 * P0) {
                    char* base = slab + (p < P0 ? 0 : 10816000);
                    p = (p < P0) ? p : p - P0;
                    int w = p % 130; int r = p / 130; int h = r % 130; int d = r / 130;
                    if (d == 0 || d == 9 || h == 0 || h == 129 || w == 0 || w == 129) {
                        uint4* q = (uint4*)(base + (size_t)p * 64);
                        q[0] = z; q[1] = z; q[2] = z; q[3] = z;
                    }
                } else if ((p -= 2 * P0) < 2 * P1) {
                    char* base = slab + 21632000 + (p < P1 ? 0 : 3345408);
                    p = (p < P1) ? p : p - P1;
                    int w = p % 66; int r = p / 66; int h = r % 66; int d = r / 66;
                    if (d == 0 || d == 5 || h == 0 || h == 65 || w == 0 || w == 65) {
                        uint4* q = (uint4*)(base + (size_t)p * 128);
#pragma unroll
                        for (int k = 0; k < 8; ++k) q[k] = z;
                    }
                } else {
                    p -= 2 * P1;
                    char* base = slab + 28322816 + (p < P2 ? 0 : 591872);
                    p = (p < P2) ? p : p - P2;
                    int w = p % 34; int r = p / 34; int h = r % 34; int d = r / 34;
                    if (d == 0 || d == 3 || h == 0 || h == 33 || w == 0 || w == 33) {
                        uint4* q = (uint4*)(base + (size_t)p * 128);
#pragma unroll
                        for (int k = 0; k < 8; ++k) q[k] = z;
                    }
                }
            }
        }
        return;
    }
    if (blockIdx.y == 30) {                // build_lists branch (200000 points)
        int i = blockIdx.x * 256 + threadIdx.x;
        if (i >= 200000) return;
        int v = p2v[i];
        int slot = atomicAdd(&cnt[v], 1);
        if (slot < 20) list[v * 20 + slot] = i;
        return;
    }
    CvtDesc de = a.d[blockIdx.y];
    int i = blockIdx.x * 256 + threadIdx.x;
    if (i >= de.n) return;
    float v = ldflex(de.src, i, *flagp);
    if (de.cin == 0) { bn[de.off + i] = v; return; }
    int cin = de.cin;
    int KB = cin >> 5, NH = de.cout >> 4;
    int co = i / (cin * 27);
    int rem = i % (cin * 27);
    int ci = rem / 27, tap = rem % 27;
    int kb = ci >> 5, q = (ci >> 3) & 3, j = ci & 7;
    int half = co >> 4, n = co & 15, lane = q * 16 + n;
    (void)KB;
    wf[de.off + ((((tap * KB + kb) * NH + half) << 9) + lane * 8 + j)] = __float2bfloat16(v);
}

// ---------------- K3: voxel-major fused VFE ----------------
// (scatter + sort + vfe + occ1 inverse-pool; numerics bit-identical to 3-kernel path)
__global__ __launch_bounds__(256) void voxel_vfe(
    const void* __restrict__ points, const void* __restrict__ voxels,
    const void* __restrict__ w_in, const void* __restrict__ s_in, const void* __restrict__ t_in,
    const int* __restrict__ coors, const int* __restrict__ cnt,
    const int* __restrict__ list, int* __restrict__ idxmap,
    float* __restrict__ occ1, __hip_bfloat16* __restrict__ hbuf,
    const int* __restrict__ flagp) {
    const int N = 200000;
    __shared__ float lw[256], lsc[32], lbi[32];
    int bf = *flagp;
    if (threadIdx.x < 256) lw[threadIdx.x] = ldflex(w_in, threadIdx.x, bf);
    if (threadIdx.x < 32) {
        lsc[threadIdx.x] = ldflex(s_in, threadIdx.x, bf);
        lbi[threadIdx.x] = ldflex(t_in, threadIdx.x, bf);
    }
    __syncthreads();
    int v = blockIdx.x * 256 + threadIdx.x;
    if (v >= 40000) return;
    if (v < 16) ((unsigned int*)(hbuf + 40000 * 32))[v] = 0u;   // zero row for holes

    int x = coors[v * 4 + 1], y = coors[v * 4 + 2], z = coors[v * 4 + 3];
    idxmap[((size_t)z * 256 + y) * 256 + x] = v;
    // occ1 inverse-pool scatter: valid d satisfy |z-2d|<=1 -> d in [z>>1, (z+1)>>1]
    for (int dd = z >> 1; dd <= ((z + 1) >> 1) && dd < 8; ++dd)
        for (int hh = y >> 1; hh <= ((y + 1) >> 1) && hh < 128; ++hh)
            for (int ww = x >> 1; ww <= ((x + 1) >> 1) && ww < 128; ++ww)
                occ1[((size_t)dd * 128 + hh) * 128 + ww] = 1.f;

    int c_ = min(cnt[v], 20);
    int idxs[20];
    for (int k = 0; k < c_; ++k) idxs[k] = list[v * 20 + k];
    for (int i = 1; i < c_; ++i) {
        int key = idxs[i]; int j = i - 1;
        while (j >= 0 && idxs[j] > key) { idxs[j + 1] = idxs[j]; --j; }
        idxs[j + 1] = key;
    }
    float vx0 = ldflex(voxels, v * 4 + 0, bf);
    float vx1 = ldflex(voxels, v * 4 + 1, bf);
    float vx2 = ldflex(voxels, v * 4 + 2, bf);
    float vx3 = ldflex(voxels, v * 4 + 3, bf);
    float acc[32];
#pragma unroll
    for (int j = 0; j < 32; ++j) acc[j] = 0.f;
    int msum = min(c_, 5);
    for (int s = 0; s < msum; ++s) {        // ascending point index = old slot order
        int i = idxs[s];
        float p0 = ldflex(points, i, bf);
        float p1 = ldflex(points, N + i, bf);
        float p2 = ldflex(points, 2 * N + i, bf);
        float p3 = ldflex(points, 3 * N + i, bf);
        float f0 = vx0 - p0, f1 = vx1 - p1, f2 = vx2 - p2, f3 = vx3 - p3;
        float mult = (s == 0) ? (float)(20 - c_ + 1) : 1.f;
#pragma unroll
        for (int oo = 0; oo < 32; ++oo) {
            float d = f0 * lw[oo * 8 + 0] + f1 * lw[oo * 8 + 1] + f2 * lw[oo * 8 + 2] +
                      f3 * lw[oo * 8 + 3] + p0 * lw[oo * 8 + 4] + p1 * lw[oo * 8 + 5] +
                      p2 * lw[oo * 8 + 6] + p3 * lw[oo * 8 + 7];
            float r = fmaxf(d * lsc[oo] + lbi[oo], 0.f) * mult;
            acc[oo] += __bfloat162float((__bf16)r);   // replicate old per-slot bf16 round
        }
    }
    __hip_bfloat16* o = hbuf + (size_t)v * 32;
#pragma unroll
    for (int g = 0; g < 4; ++g) {
        bf16x8 pack;
#pragma unroll
        for (int j = 0; j < 8; ++j) pack[j] = (__bf16)(acc[g * 8 + j] * 0.05f);
        *(bf16x8*)(void*)(o + g * 8) = pack;
    }
}

// ---------------- conv0: sparse gather implicit-GEMM MFMA, 4 tiles/wave (+pool tail) ----
__global__ __launch_bounds__(256) void conv0_mfma(
    const __hip_bfloat16* __restrict__ hb, const int* __restrict__ idxmap,
    __hip_bfloat16* __restrict__ out,                 // padded (10,130,130,32)
    const __hip_bfloat16* __restrict__ wf, const float* __restrict__ bns,
    const float* __restrict__ occ, float* __restrict__ pdst) {
    if (blockIdx.x >= 512) {               // tail: occ1 -> occ2 (16384 cells, 64 blocks)
        int t = (blockIdx.x - 512) * 256 + threadIdx.x;
        if (t < 16384) pool_cell(occ, pdst, 8, 128, 128, 4, 64, 64, 2, t);
        return;
    }
    int bid = xcd_swz(blockIdx.x, 512);
    int wave = (bid * 256 + threadIdx.x) >> 6;        // 2048 waves (4-tile groups)
    int lane = threadIdx.x & 63;
    int twg = wave & 1; int r = wave >> 1;
    int h = r & 127;    int d = r >> 7;
    int w0 = twg * 64;
    int q = lane >> 4, n = lane & 15;

    f32x4 acc[4][2];
#pragma unroll
    for (int t = 0; t < 4; ++t)
#pragma unroll
        for (int i = 0; i < 2; ++i) acc[t][i] = (f32x4){0.f, 0.f, 0.f, 0.f};

    const float* op = occ + ((size_t)(d * 128 + h)) * 128 + w0;
    bool any = false;
#pragma unroll
    for (int t = 0; t < 4; ++t) any = any || (op[t * 16 + n] != 0.f);
    if (__ballot(any)) {
#pragma unroll
        for (int kd = 0; kd < 3; ++kd) {
            int id = d * 2 + kd - 1;
            if (id < 0) continue;
#pragma unroll
            for (int kh = 0; kh < 3; ++kh) {
                int ih = h * 2 + kh - 1;
                if (ih < 0) continue;
                const int* ip = idxmap + ((size_t)id * 256 + ih) * 256;
#pragma unroll
                for (int kw = 0; kw < 3; ++kw) {
                    int tap = (kd * 3 + kh) * 3 + kw;
                    bf16x8 A[4];
#pragma unroll
                    for (int t = 0; t < 4; ++t) {
                        int iw = (w0 + t * 16 + n) * 2 + kw - 1;
                        int v = (iw >= 0) ? ip[iw] : -1;
                        int vv = (v >= 0) ? v : 40000;          // row 40000 = zeros
                        A[t] = ldfrag(hb + (size_t)vv * 32 + q * 8);
                    }
#pragma unroll
                    for (int i = 0; i < 2; ++i) {
                        bf16x8 B = ldfrag(wf + ((tap * 2 + i) << 9) + lane * 8);
#pragma unroll
                        for (int t = 0; t < 4; ++t)
                            acc[t][i] = __builtin_amdgcn_mfma_f32_16x16x32_bf16(
                                A[t], B, acc[t][i], 0, 0, 0);
                    }
                }
            }
        }
    }
#pragma unroll
    for (int t = 0; t < 4; ++t)
#pragma unroll
        for (int half = 0; half < 2; ++half) {
            int co = half * 16 + n;
            float s = bns[co], b = bns[32 + co];
#pragma unroll
            for (int r2 = 0; r2 < 4; ++r2) {
                int mm = t * 16 + q * 4 + r2;
                float oc = op[mm];
                float vv = fmaxf(acc[t][half][r2] * s + b, 0.f) * oc;
                out[((size_t)((d + 1) * 130 + (h + 1)) * 130 + (w0 + mm + 1)) * 32 + co] =
                    __float2bfloat16(vv);
            }
        }
}

// ---------------- dense implicit-GEMM MFMA conv: TILES tiles, NHP halves (+pool tail) ----
template <int CIN, int COUT, int STRIDE, int NHP, int TILES>
__global__ __launch_bounds__(256) void conv_mfma(
    const __hip_bfloat16* __restrict__ in, __hip_bfloat16* __restrict__ out,
    const __hip_bfloat16* __restrict__ wf, const float* __restrict__ bns,
    const float* __restrict__ occ,
    int Hp, int Wp, int Do, int Ho, int Wo, int OHp, int OWp,
    int mainBlocks, const float* psrc, float* pdst,
    int pDi, int pHi, int pWi, int pDo, int pHo, int pWo, int pStride, int pcount) {
    constexpr int KB = CIN / 32, NH = COUT / 16, NG = NH / NHP;
    if ((int)blockIdx.x >= mainBlocks) {
        int t = (blockIdx.x - mainBlocks) * 256 + threadIdx.x;
        if (t < pcount) pool_cell(psrc, pdst, pDi, pHi, pWi, pDo, pHo, pWo, pStride, t);
        return;
    }
    int bid = xcd_swz(blockIdx.x, mainBlocks);
    int gw = (bid * 256 + threadIdx.x) >> 6;
    int lane = threadIdx.x & 63;
    int hg = gw % NG;
    int wave = gw / NG;
    int ngw = (Wo >> 4) / TILES;
    int twg = wave % ngw; int r = wave / ngw;
    int h = r % Ho; int d = r / Ho;
    int w0 = twg * TILES * 16;
    int q = lane >> 4, n = lane & 15;

    f32x4 acc[TILES][NHP];
#pragma unroll
    for (int t = 0; t < TILES; ++t)
#pragma unroll
        for (int i = 0; i < NHP; ++i) acc[t][i] = (f32x4){0.f, 0.f, 0.f, 0.f};

    const float* op = occ + ((size_t)(d * Ho + h)) * Wo + w0;
    bool any = false;
#pragma unroll
    for (int t = 0; t < TILES; ++t) any = any || (op[t * 16 + n] != 0.f);
    if (__ballot(any)) {
#pragma unroll
        for (int kd = 0; kd < 3; ++kd) {
#pragma unroll
            for (int kh = 0; kh < 3; ++kh) {
#pragma unroll
                for (int kw = 0; kw < 3; ++kw) {
                    int tap = (kd * 3 + kh) * 3 + kw;
                    const __hip_bfloat16* ip = in +
                        ((size_t)((d * STRIDE + kd) * Hp + (h * STRIDE + kh)) * Wp +
                         (w0 * STRIDE + kw)) * CIN;
#pragma unroll
                    for (int kb = 0; kb < KB; ++kb) {
                        bf16x8 A[TILES];
#pragma unroll
                        for (int t = 0; t < TILES; ++t)
                            A[t] = ldfrag(ip + ((t * 16 + n) * STRIDE) * CIN + kb * 32 + q * 8);
#pragma unroll
                        for (int i = 0; i < NHP; ++i) {
                            int half = hg * NHP + i;
                            bf16x8 B = ldfrag(
                                wf + (((tap * KB + kb) * NH + half) << 9) + lane * 8);
#pragma unroll
                            for (int t = 0; t < TILES; ++t)
                                acc[t][i] = __builtin_amdgcn_mfma_f32_16x16x32_bf16(
                                    A[t], B, acc[t][i], 0, 0, 0);
                        }
                    }
                }
            }
        }
    }
#pragma unroll
    for (int t = 0; t < TILES; ++t)
#pragma unroll
        for (int i = 0; i < NHP; ++i) {
            int co = (hg * NHP + i) * 16 + n;
            float s = bns[co], b = bns[COUT + co];
#pragma unroll
            for (int r2 = 0; r2 < 4; ++r2) {
                int mm = t * 16 + q * 4 + r2;
                float oc = op[mm];
                float vv = fmaxf(acc[t][i][r2] * s + b, 0.f) * oc;
                out[((size_t)((d + 1) * OHp + (h + 1)) * OWp + (w0 + mm + 1)) * COUT + co] =
                    __float2bfloat16(vv);
            }
        }
}

// ---------------- final conv 64->128, NCDHW typed output ----------------
__global__ __launch_bounds__(256) void conv_out_mfma(
    const __hip_bfloat16* __restrict__ in,            // padded (4,34,34,64)
    void* __restrict__ outv,
    const __hip_bfloat16* __restrict__ wf, const float* __restrict__ bns,
    const float* __restrict__ occ, const int* __restrict__ flagp) {
    constexpr int KB = 2, NH = 8;
    int bid = xcd_swz(blockIdx.x, 256);
    int gw = (bid * 256 + threadIdx.x) >> 6;          // 1024 waves
    int lane = threadIdx.x & 63;
    int hg = gw & 7;
    int wave = gw >> 3;
    int tw = wave & 1; int r = wave >> 1;
    int h = r & 31;    int d = r >> 5;
    int w0 = tw * 16;
    int q = lane >> 4, n = lane & 15;

    f32x4 acc = {0.f, 0.f, 0.f, 0.f};
    const float* op = occ + ((size_t)(d * 32 + h)) * 32 + w0;
    float ocn = op[n];
    if (__ballot(ocn != 0.f)) {
#pragma unroll
        for (int kd = 0; kd < 3; ++kd) {
#pragma unroll
            for (int kh = 0; kh < 3; ++kh) {
#pragma unroll
                for (int kw = 0; kw < 3; ++kw) {
                    int tap = (kd * 3 + kh) * 3 + kw;
                    const __hip_bfloat16* ip = in +
                        ((size_t)((d + kd) * 34 + (h + kh)) * 34 + (w0 + kw)) * 64;
#pragma unroll
                    for (int kb = 0; kb < KB; ++kb) {
                        bf16x8 A = ldfrag(ip + n * 64 + kb * 32 + q * 8);
                        acc = __builtin_amdgcn_mfma_f32_16x16x32_bf16(
                            A, ldfrag(wf + (((tap * KB + kb) * NH + hg) << 9) + lane * 8),
                            acc, 0, 0, 0);
                    }
                }
            }
        }
    }
    int bf = *flagp;
    int co = hg * 16 + n;
    float s = bns[co], b = bns[128 + co];
#pragma unroll
    for (int r2 = 0; r2 < 4; ++r2) {
        int mm = q * 4 + r2;
        float oc = op[mm];
        float vv = fmaxf(acc[r2] * s + b, 0.f) * oc;
        size_t off = (size_t)co * 2048 + ((size_t)(d * 32 + h)) * 32 + (w0 + mm);
        if (bf) ((__hip_bfloat16*)outv)[off] = __float2bfloat16(vv);
        else    ((float*)outv)[off] = vv;
    }
}

// ---------------- launch (13 dispatches) ----------------
extern "C" void kernel_launch(void* const* d_in, const int* in_sizes, int n_in,
                              void* d_out, int out_size, void* d_ws, size_t ws_size,
                              hipStream_t stream) {
    const void* points = d_in[0];
    const void* voxels = d_in[1];
    const void* w_in   = d_in[2];
    const void* s_in   = d_in[3];
    const void* t_in   = d_in[4];
    const int* coors = (const int*)d_in[35];
    const int* p2v   = (const int*)d_in[36];

    char* ws = (char*)d_ws;
    __hip_bfloat16* wf   = (__hip_bfloat16*)(ws + 0);
    float*          bn   = (float*)(ws + 1835008);
    __hip_bfloat16* hbuf = (__hip_bfloat16*)(ws + 4194304);    // 40001*32 bf16
    int*   idxmap = (int*)(ws + 8388608);                      // 4 MiB
    __hip_bfloat16* xP0A = (__hip_bfloat16*)(ws + 12582912);
    __hip_bfloat16* xP0B = (__hip_bfloat16*)(ws + 23398912);
    __hip_bfloat16* xP1A = (__hip_bfloat16*)(ws + 34214912);
    __hip_bfloat16* xP1B = (__hip_bfloat16*)(ws + 37560320);
    __hip_bfloat16* xP2A = (__hip_bfloat16*)(ws + 40905728);
    __hip_bfloat16* xP2B = (__hip_bfloat16*)(ws + 41497600);
    float* occ1 = (float*)(ws + 42089472);                     // 512 KB
    float* occ2 = (float*)(ws + 42613760);
    float* occ3 = (float*)(ws + 42679296);
    float* occ4 = (float*)(ws + 42687488);
    int*   cnt  = (int*)(ws + 42695680);
    int*   list = (int*)(ws + 43015680);                       // 3.2 MB
    int*   flag = (int*)(ws + 47015680);

    // K1: cnt=0 + dtype probe (tiny; must precede K2's list atomics)
    init_cnt<<<40, 256, 0, stream>>>(cnt, points, flag);

    static const int widx[30] = {5,6,7, 8,9,10, 11,12,13, 14,15,16, 17,18,19,
                                 20,21,22, 23,24,25, 26,27,28, 29,30,31, 32,33,34};
    static const int wnn[30]  = {27648,32,32, 27648,32,32, 27648,32,32,
                                 55296,64,64, 110592,64,64, 110592,64,64,
                                 110592,64,64, 110592,64,64, 110592,64,64,
                                 221184,128,128};
    static const int woff[30] = {0,0,32, 27648,64,96, 55296,128,160,
                                 82944,192,256, 138240,320,384, 248832,448,512,
                                 359424,576,640, 470016,704,768, 580608,832,896,
                                 691200,960,1088};
    static const int wcin[30]  = {32,0,0, 32,0,0, 32,0,0, 32,0,0, 64,0,0,
                                  64,0,0, 64,0,0, 64,0,0, 64,0,0, 64,0,0};
    static const int wcout[30] = {32,0,0, 32,0,0, 32,0,0, 64,0,0, 64,0,0,
                                  64,0,0, 64,0,0, 64,0,0, 64,0,0, 128,0,0};
    CvtArgs ca;
    for (int i = 0; i < 30; ++i)
        ca.d[i] = CvtDesc{ d_in[widx[i]], wnn[i], woff[i], wcin[i], wcout[i] };
    // K2: cvt_weights (y<30) + build_lists (y==30) + init fills (y==31)
    cvt_build<<<dim3(864, 32), 256, 0, stream>>>(ca, wf, bn, flag, p2v, cnt, list,
                                                 idxmap, occ1, (char*)xP0A);

    // K3: fused voxel-major VFE (scatter + sort + vfe + occ1)
    voxel_vfe<<<157, 256, 0, stream>>>(points, voxels, w_in, s_in, t_in,
                                       coors, cnt, list, idxmap, occ1, hbuf, flag);

    // stage 0: -> (8,128,128) x32   (512 main blocks; conv0 tail computes occ2)
    conv0_mfma<<<576, 256, 0, stream>>>(hbuf, idxmap, xP0A, wf + 0, bn + 0, occ1, occ2);
    conv_mfma<32, 32, 1, 2, 4><<<520, 256, 0, stream>>>(
        xP0A, xP0B, wf + 27648, bn + 64, occ1, 130, 130, 8, 128, 128, 130, 130,
        512, occ2, occ3, 4, 64, 64, 2, 32, 32, 2, 2048);
    conv_mfma<32, 32, 1, 2, 4><<<520, 256, 0, stream>>>(
        xP0B, xP0A, wf + 55296, bn + 128, occ1, 130, 130, 8, 128, 128, 130, 130,
        512, occ3, occ4, 2, 32, 32, 2, 32, 32, 1, 2048);

    // stage 1: -> (4,64,64) x64
    conv_mfma<32, 64, 2, 2, 2><<<256, 256, 0, stream>>>(
        xP0A, xP1A, wf + 82944, bn + 192, occ2, 130, 130, 4, 64, 64, 66, 66,
        256, nullptr, nullptr, 0, 0, 0, 0, 0, 0, 1, 0);
    conv_mfma<64, 64, 1, 2, 2><<<256, 256, 0, stream>>>(
        xP1A, xP1B, wf + 138240, bn + 320, occ2, 66, 66, 4, 64, 64, 66, 66,
        256, nullptr, nullptr, 0, 0, 0, 0, 0, 0, 1, 0);
    conv_mfma<64, 64, 1, 2, 2><<<256, 256, 0, stream>>>(
        xP1B, xP1A, wf + 248832, bn + 448, occ2, 66, 66, 4, 64, 64, 66, 66,
        256, nullptr, nullptr, 0, 0, 0, 0, 0, 0, 1, 0);

    // stage 2: -> (2,32,32) x64
    conv_mfma<64, 64, 2, 1, 1><<<128, 256, 0, stream>>>(
        xP1A, xP2A, wf + 359424, bn + 576, occ3, 66, 66, 2, 32, 32, 34, 34,
        128, nullptr, nullptr, 0, 0, 0, 0, 0, 0, 1, 0);
    conv_mfma<64, 64, 1, 1, 1><<<128, 256, 0, stream>>>(
        xP2A, xP2B, wf + 470016, bn + 704, occ3, 34, 34, 2, 32, 32, 34, 34,
        128, nullptr, nullptr, 0, 0, 0, 0, 0, 0, 1, 0);
    conv_mfma<64, 64, 1, 1, 1><<<128, 256, 0, stream>>>(
        xP2B, xP2A, wf + 580608, bn + 832, occ3, 34, 34, 2, 32, 32, 34, 34,
        128, nullptr, nullptr, 0, 0, 0, 0, 0, 0, 1, 0);

    // final: -> (128,2,32,32)
    conv_out_mfma<<<256, 256, 0, stream>>>(xP2A, d_out, wf + 691200, bn + 960, occ4, flag);
}